// Round 6
// baseline (457.656 us; speedup 1.0000x reference)
//
#include <hip/hip_runtime.h>

typedef _Float16 h8 __attribute__((ext_vector_type(8)));
typedef _Float16 h2 __attribute__((ext_vector_type(2)));
typedef float f4 __attribute__((ext_vector_type(4)));
typedef unsigned u4 __attribute__((ext_vector_type(4)));

#define H 128
#define HH2 256
#define M_OUT 2048
#define CB 128           // chunk blocks for histogram/scatter
#define MAXBUCK 1024     // supports N <= 131072

__device__ __forceinline__ float u2f_lo(unsigned v) {
  union { unsigned short s; _Float16 h; } c; c.s = (unsigned short)(v & 0xffffu); return (float)c.h;
}
__device__ __forceinline__ float u2f_hi(unsigned v) {
  union { unsigned short s; _Float16 h; } c; c.s = (unsigned short)(v >> 16); return (float)c.h;
}
__device__ __forceinline__ h2 as_h2(unsigned v) {
  union { unsigned u; h2 h; } c; c.u = v; return c.h;
}

// ---- weight prep: transpose + fp16 convert. mat 0 = W_embed, 1+2l = Wtop_l, 2+2l = Wbot_l
__global__ void prep_weights(const float* __restrict__ We, const float* __restrict__ Wm,
                             _Float16* __restrict__ WtAll) {
  int gid = blockIdx.x * 256 + threadIdx.x;
  if (gid >= 7 * 16384) return;
  int m = gid >> 14, rem = gid & 16383, c = rem >> 7, k = rem & 127;
  float v;
  if (m == 0) v = We[k * H + c];
  else {
    int l = (m - 1) >> 1, bot = (m - 1) & 1;
    v = Wm[l * (2 * H * H) + (bot * H + k) * H + c];
  }
  WtAll[m * 16384 + c * H + k] = (_Float16)v;   // row = out-col, contiguous k
}

// ================= CSR build: atomic-free two-level counting sort =================
// bucket = tgt >> 7  (128 nodes/bucket)

__global__ void hist_k(const int* __restrict__ ei, int E, int chunk,
                       int* __restrict__ hist, int nbuck) {
  __shared__ int bins[MAXBUCK];
  for (int i = threadIdx.x; i < nbuck; i += blockDim.x) bins[i] = 0;
  __syncthreads();
  int s = blockIdx.x * chunk, e = min(s + chunk, E);
  for (int i = s + threadIdx.x; i < e; i += blockDim.x)
    atomicAdd(&bins[ei[E + i] >> 7], 1);
  __syncthreads();
  for (int i = threadIdx.x; i < nbuck; i += blockDim.x)
    hist[blockIdx.x * nbuck + i] = bins[i];
}

// per-bucket exclusive scan over the CB blocks; totals[j] = bucket size
__global__ void scanb_k(int* __restrict__ hist, int* __restrict__ totals, int nbuck) {
  __shared__ int sm[CB];
  int j = blockIdx.x, b = threadIdx.x;
  int v = hist[b * nbuck + j];
  sm[b] = v; __syncthreads();
  for (int off = 1; off < CB; off <<= 1) {
    int add = (b >= off) ? sm[b - off] : 0; __syncthreads();
    sm[b] += add; __syncthreads();
  }
  hist[b * nbuck + j] = sm[b] - v;      // exclusive over blocks
  if (b == CB - 1) totals[j] = sm[b];
}

// exclusive scan of bucket totals -> bucket_base; also zeroes gsum/gcnt for pool
__global__ void scant_k(const int* __restrict__ totals, int* __restrict__ bbase,
                        int* __restrict__ rowp, int nbuck, int E, int N,
                        float* __restrict__ gsum, float* __restrict__ gcnt) {
  __shared__ int sm[MAXBUCK];
  int t = threadIdx.x;
  int v = (t < nbuck) ? totals[t] : 0;
  sm[t] = v; __syncthreads();
  for (int off = 1; off < MAXBUCK; off <<= 1) {
    int add = (t >= off) ? sm[t - off] : 0; __syncthreads();
    sm[t] += add; __syncthreads();
  }
  if (t < nbuck) bbase[t] = sm[t] - v;
  if (t == 0) { bbase[nbuck] = E; rowp[N] = E; }
  for (int i = t; i < 16 * H; i += MAXBUCK) gsum[i] = 0.f;
  if (t < 16) gcnt[t] = 0.f;
}

// scatter packed (ltgt<<25)|src into bucket-major order, LDS cursors (no global atomics)
__global__ void scat_k(const int* __restrict__ ei, int E, int chunk,
                       const int* __restrict__ hist, const int* __restrict__ bbase,
                       unsigned* __restrict__ pairs, int nbuck) {
  __shared__ int cur[MAXBUCK];
  for (int i = threadIdx.x; i < nbuck; i += blockDim.x)
    cur[i] = bbase[i] + hist[blockIdx.x * nbuck + i];
  __syncthreads();
  int s = blockIdx.x * chunk, e = min(s + chunk, E);
  for (int i = s + threadIdx.x; i < e; i += blockDim.x) {
    int sv = ei[i], tv = ei[E + i];
    int pos = atomicAdd(&cur[tv >> 7], 1);
    pairs[pos] = ((unsigned)(tv & 127) << 25) | (unsigned)sv;
  }
}

// per-bucket counting sort: 128-bin LDS histogram + scan -> row_ptr, then scatter srcs
__global__ void build_k(const unsigned* __restrict__ pairs, const int* __restrict__ bbase,
                        int* __restrict__ rowp, int* __restrict__ srcs, int N) {
  __shared__ int h128[128];
  __shared__ int pre[128];
  int j = blockIdx.x, t = threadIdx.x;
  int base = bbase[j], end = bbase[j + 1];
  if (t < 128) h128[t] = 0;
  __syncthreads();
  for (int i = base + t; i < end; i += blockDim.x)
    atomicAdd(&h128[pairs[i] >> 25], 1);
  __syncthreads();
  if (t < 128) pre[t] = h128[t];
  __syncthreads();
  for (int off = 1; off < 128; off <<= 1) {
    int add = (t < 128 && t >= off) ? pre[t - off] : 0; __syncthreads();
    if (t < 128) pre[t] += add; __syncthreads();
  }
  if (t < 128) {
    int excl = pre[t] - h128[t];
    int node = j * 128 + t;
    if (node < N) rowp[node] = base + excl;
    h128[t] = excl;                        // reuse as cursor
  }
  __syncthreads();
  for (int i = base + t; i < end; i += blockDim.x) {
    unsigned p = pairs[i];
    int pos = atomicAdd(&h128[p >> 25], 1);
    srcs[base + pos] = (int)(p & 0x1ffffff);
  }
}

// ================= embed GEMM: hh = fp16(x @ W_embed + b_embed) =================
__global__ __launch_bounds__(256, 2) void gemm_embed(
    const float* __restrict__ Af, const _Float16* __restrict__ Wt,
    const float* __restrict__ bias, _Float16* __restrict__ outH, int ntiles)
{
  int lane = threadIdx.x & 63;
  int wid = blockIdx.x * 4 + (threadIdx.x >> 6);
  int nw = gridDim.x * 4;
  int sel = lane & 15, kg = lane >> 4;

  h8 bfrag[8][4];
#pragma unroll
  for (int ct = 0; ct < 8; ++ct)
#pragma unroll
    for (int ks = 0; ks < 4; ++ks)
      bfrag[ct][ks] = *(const h8*)(Wt + (ct * 16 + sel) * H + ks * 32 + kg * 8);

  auto load_a = [&](int row, int ks) -> h8 {
    const float* b = Af + row * H + ks * 32 + kg * 8;
    f4 a0 = *(const f4*)b, a1 = *(const f4*)(b + 4);
    h8 r;
    r[0] = (_Float16)a0.x; r[1] = (_Float16)a0.y; r[2] = (_Float16)a0.z; r[3] = (_Float16)a0.w;
    r[4] = (_Float16)a1.x; r[5] = (_Float16)a1.y; r[6] = (_Float16)a1.z; r[7] = (_Float16)a1.w;
    return r;
  };

  int t = wid;
  h8 afrag[4];
  if (t < ntiles) {
#pragma unroll
    for (int ks = 0; ks < 4; ++ks) afrag[ks] = load_a(t * 16 + sel, ks);
  }
  while (t < ntiles) {
    int tn = t + nw;
    h8 anext[4];
    if (tn < ntiles) {
#pragma unroll
      for (int ks = 0; ks < 4; ++ks) anext[ks] = load_a(tn * 16 + sel, ks);
    }
    f4 acc[8];
#pragma unroll
    for (int ct = 0; ct < 8; ++ct) acc[ct] = (f4){0.f, 0.f, 0.f, 0.f};
#pragma unroll
    for (int ks = 0; ks < 4; ++ks)
#pragma unroll
      for (int ct = 0; ct < 8; ++ct)
        acc[ct] = __builtin_amdgcn_mfma_f32_16x16x32_f16(afrag[ks], bfrag[ct][ks], acc[ct], 0, 0, 0);
#pragma unroll
    for (int ct = 0; ct < 8; ++ct) {
      int c = ct * 16 + sel;
      float bv = bias[c];
#pragma unroll
      for (int j = 0; j < 4; ++j) {
        int r = t * 16 + kg * 4 + j;
        outH[r * H + c] = (_Float16)(acc[ct][j] + bv);
      }
    }
#pragma unroll
    for (int ks = 0; ks < 4; ++ks) afrag[ks] = anext[ks];
    t = tn;
  }
}

// ================= paired message GEMM (wave-specialized) =================
// waves 0-1: Pout = fp16(hh @ Wtop)
// waves 2-3: aggH = fp16((hh @ Wbot + bm) * indeg)
// Paired waves process the same tile sequence -> hh read once, L1/L2 shared.
__global__ __launch_bounds__(256, 2) void gemm_pair(
    const _Float16* __restrict__ Ah, const _Float16* __restrict__ WtTop,
    const _Float16* __restrict__ WtBot, const float* __restrict__ bias,
    const int* __restrict__ row_ptr, _Float16* __restrict__ Pout,
    _Float16* __restrict__ aggH, int ntiles)
{
  int lane = threadIdx.x & 63;
  int wiw = threadIdx.x >> 6;          // 0..3
  int role = wiw >> 1;                 // 0: P, 1: aggQ
  int wid = blockIdx.x * 2 + (wiw & 1);
  int nw = gridDim.x * 2;
  int sel = lane & 15, kg = lane >> 4;
  const _Float16* Wt = role ? WtBot : WtTop;

  h8 bfrag[8][4];
#pragma unroll
  for (int ct = 0; ct < 8; ++ct)
#pragma unroll
    for (int ks = 0; ks < 4; ++ks)
      bfrag[ct][ks] = *(const h8*)(Wt + (ct * 16 + sel) * H + ks * 32 + kg * 8);

  int t = wid;
  h8 afrag[4];
  if (t < ntiles) {
#pragma unroll
    for (int ks = 0; ks < 4; ++ks)
      afrag[ks] = *(const h8*)(Ah + (t * 16 + sel) * H + ks * 32 + kg * 8);
  }
  while (t < ntiles) {
    int tn = t + nw;
    h8 anext[4];
    if (tn < ntiles) {
#pragma unroll
      for (int ks = 0; ks < 4; ++ks)
        anext[ks] = *(const h8*)(Ah + (tn * 16 + sel) * H + ks * 32 + kg * 8);
    }
    f4 acc[8];
#pragma unroll
    for (int ct = 0; ct < 8; ++ct) acc[ct] = (f4){0.f, 0.f, 0.f, 0.f};
#pragma unroll
    for (int ks = 0; ks < 4; ++ks)
#pragma unroll
      for (int ct = 0; ct < 8; ++ct)
        acc[ct] = __builtin_amdgcn_mfma_f32_16x16x32_f16(afrag[ks], bfrag[ct][ks], acc[ct], 0, 0, 0);

    if (role == 0) {
#pragma unroll
      for (int ct = 0; ct < 8; ++ct) {
        int c = ct * 16 + sel;
#pragma unroll
        for (int j = 0; j < 4; ++j) {
          int r = t * 16 + kg * 4 + j;
          Pout[r * H + c] = (_Float16)acc[ct][j];
        }
      }
    } else {
      float indeg[4];
#pragma unroll
      for (int j = 0; j < 4; ++j) {
        int r = t * 16 + kg * 4 + j;
        indeg[j] = (float)(row_ptr[r + 1] - row_ptr[r]);
      }
#pragma unroll
      for (int ct = 0; ct < 8; ++ct) {
        int c = ct * 16 + sel;
        float bv = bias[c];
#pragma unroll
        for (int j = 0; j < 4; ++j) {
          int r = t * 16 + kg * 4 + j;
          aggH[r * H + c] = (_Float16)((acc[ct][j] + bv) * indeg[j]);
        }
      }
    }
#pragma unroll
    for (int ks = 0; ks < 4; ++ks) afrag[ks] = anext[ks];
    t = tn;
  }
}

// ---- per-node gather of P rows + h update: hh = relu(hh + aggH + sum P[src])
// Quarter-wave (16 lanes x uint4 = 256B) reads one P row -> 4 edges per step.
// Packed fp16 accumulate; fp32 finish. All shfls at wave-uniform control points.
// Streaming operands (srcs, aggH, hh) use nontemporal hints to keep L2 for P.
__global__ __launch_bounds__(256) void agg_update(
    const _Float16* __restrict__ P, const int* __restrict__ rowp,
    const int* __restrict__ srcs, const _Float16* __restrict__ aggH,
    _Float16* hh, int N)
{
  int node = blockIdx.x * 4 + (threadIdx.x >> 6);
  if (node >= N) return;
  int lane = threadIdx.x & 63;
  int q = lane >> 4, li = lane & 15;
  const uint4* P4 = (const uint4*)P;
  h2 a0 = (h2)0, a1 = (h2)0, a2 = (h2)0, a3 = (h2)0;
  int e = rowp[node], end = rowp[node + 1];
  while (e < end) {
    int cnt = min(end - e, 64);          // wave-uniform
    int myS = (lane < cnt) ? __builtin_nontemporal_load(&srcs[e + lane]) : 0;
    int j = 0;
    for (; j + 16 <= cnt; j += 16) {     // 16 edges, 4 loads in flight
      int s0 = __shfl(myS, j + q);
      int s1 = __shfl(myS, j + 4 + q);
      int s2 = __shfl(myS, j + 8 + q);
      int s3 = __shfl(myS, j + 12 + q);
      uint4 v0 = P4[s0 * 16 + li], v1 = P4[s1 * 16 + li];
      uint4 v2 = P4[s2 * 16 + li], v3 = P4[s3 * 16 + li];
      a0 += as_h2(v0.x) + as_h2(v1.x) + as_h2(v2.x) + as_h2(v3.x);
      a1 += as_h2(v0.y) + as_h2(v1.y) + as_h2(v2.y) + as_h2(v3.y);
      a2 += as_h2(v0.z) + as_h2(v1.z) + as_h2(v2.z) + as_h2(v3.z);
      a3 += as_h2(v0.w) + as_h2(v1.w) + as_h2(v2.w) + as_h2(v3.w);
    }
    for (; j + 8 <= cnt; j += 8) {       // 8 edges, 2 loads
      int s0 = __shfl(myS, j + q);
      int s1 = __shfl(myS, j + 4 + q);
      uint4 v0 = P4[s0 * 16 + li], v1 = P4[s1 * 16 + li];
      a0 += as_h2(v0.x) + as_h2(v1.x);
      a1 += as_h2(v0.y) + as_h2(v1.y);
      a2 += as_h2(v0.z) + as_h2(v1.z);
      a3 += as_h2(v0.w) + as_h2(v1.w);
    }
    for (; j < cnt; j += 4) {            // tail: predicated load, uniform shfl exec
      int jj = j + q;
      int s = __shfl(myS, (jj < cnt) ? jj : (cnt - 1));
      if (jj < cnt) {
        uint4 v = P4[s * 16 + li];
        a0 += as_h2(v.x); a1 += as_h2(v.y);
        a2 += as_h2(v.z); a3 += as_h2(v.w);
      }
    }
    e += cnt;
  }
  // unpack to fp32, reduce across the 4 quarter-waves
  float f[8] = { (float)a0[0], (float)a0[1], (float)a1[0], (float)a1[1],
                 (float)a2[0], (float)a2[1], (float)a3[0], (float)a3[1] };
#pragma unroll
  for (int i = 0; i < 8; ++i) {
    f[i] += __shfl_xor(f[i], 16);
    f[i] += __shfl_xor(f[i], 32);
  }
  if (q == 0) {
    int idx = node * 16 + li;            // row = 16 uint4
    u4 hv = __builtin_nontemporal_load(((const u4*)hh) + idx);
    u4 av = __builtin_nontemporal_load(((const u4*)aggH) + idx);
    union { _Float16 h[8]; u4 u; } pk;
#pragma unroll
    for (int i = 0; i < 4; ++i) {
      float r0 = fmaxf(u2f_lo(hv[i]) + u2f_lo(av[i]) + f[2 * i], 0.f);
      float r1 = fmaxf(u2f_hi(hv[i]) + u2f_hi(av[i]) + f[2 * i + 1], 0.f);
      pk.h[2 * i] = (_Float16)r0; pk.h[2 * i + 1] = (_Float16)r1;
    }
    __builtin_nontemporal_store(pk.u, ((u4*)hh) + idx);
  }
}

// ---- mean pool (batch sorted): fp16 input, 4 row-substreams x 64 u32-cols
__global__ void pool_k(const _Float16* __restrict__ hh, const int* __restrict__ batch,
                       float* __restrict__ gsum, float* __restrict__ gcnt, int N)
{
  int t = threadIdx.x, c2 = t & 63, sub = t >> 6;
  int per = (N + gridDim.x - 1) / gridDim.x;
  int s = blockIdx.x * per;
  int e = s + per; if (e > N) e = N;
  const unsigned* hu = (const unsigned*)hh;
  float a0 = 0.f, a1 = 0.f; int cnt = 0, cur = -1;
  for (int n = s + sub; n < e; n += 4) {
    int b = batch[n];
    if (b != cur) {
      if (cur >= 0) {
        atomicAdd(&gsum[cur * H + c2 * 2], a0);
        atomicAdd(&gsum[cur * H + c2 * 2 + 1], a1);
        if (c2 == 0) atomicAdd(&gcnt[cur], (float)cnt);
      }
      a0 = 0.f; a1 = 0.f; cnt = 0; cur = b;
    }
    unsigned v = __builtin_nontemporal_load(&hu[n * 64 + c2]);
    a0 += u2f_lo(v); a1 += u2f_hi(v); ++cnt;
  }
  if (cur >= 0) {
    atomicAdd(&gsum[cur * H + c2 * 2], a0);
    atomicAdd(&gsum[cur * H + c2 * 2 + 1], a1);
    if (c2 == 0) atomicAdd(&gcnt[cur], (float)cnt);
  }
}

// ---- fused readout: g -> hidden (relu) -> logits -> sigmoid*2pi
__global__ void readout_k(const float* __restrict__ gsum, const float* __restrict__ gcnt,
                          const float* __restrict__ W1, const float* __restrict__ b1,
                          const float* __restrict__ W2, const float* __restrict__ b2,
                          float* __restrict__ out)
{
  int b = blockIdx.x, j = threadIdx.x;
  __shared__ float g[H];
  __shared__ float hid[HH2];
  if (j < H) g[j] = gsum[b * H + j] / fmaxf(gcnt[b], 1.f);
  __syncthreads();
  float s = b1[j];
  for (int k = 0; k < H; ++k) s += g[k] * W1[k * HH2 + j];
  hid[j] = fmaxf(s, 0.f);
  __syncthreads();
#pragma unroll
  for (int m8 = 0; m8 < 8; ++m8) {
    int m = m8 * 256 + j;
    float v = b2[m];
    for (int k = 0; k < HH2; ++k) v += hid[k] * W2[k * M_OUT + m];
    out[b * M_OUT + m] = 6.283185307179586f / (1.f + expf(-v));
  }
}

extern "C" void kernel_launch(void* const* d_in, const int* in_sizes, int n_in,
                              void* d_out, int out_size, void* d_ws, size_t ws_size,
                              hipStream_t stream) {
  const float* x       = (const float*)d_in[0];
  const int*   ei      = (const int*)d_in[1];
  const int*   batch   = (const int*)d_in[2];
  const float* W_embed = (const float*)d_in[3];
  const float* b_embed = (const float*)d_in[4];
  const float* Wm      = (const float*)d_in[5];
  const float* bm      = (const float*)d_in[6];
  const float* W1      = (const float*)d_in[7];
  const float* b1      = (const float*)d_in[8];
  const float* W2      = (const float*)d_in[9];
  const float* b2      = (const float*)d_in[10];
  float* out = (float*)d_out;

  const int N = in_sizes[0] / H;
  const int E = in_sizes[1] / 2;
  const int nbuck = (N + 127) >> 7;
  const int chunk = (E + CB - 1) / CB;

  char* p = (char*)d_ws;
  auto carve = [&](size_t bytes) { void* r = (void*)p; p += (bytes + 255) & ~(size_t)255; return r; };
  _Float16*  hh      = (_Float16*)carve((size_t)N * H * 2);
  _Float16*  aggH    = (_Float16*)carve((size_t)N * H * 2);
  _Float16*  Pbuf    = (_Float16*)carve((size_t)N * H * 2);
  int*       row_ptr = (int*)carve((size_t)(N + 1) * 4);
  int*       srcs    = (int*)carve((size_t)E * 4);
  unsigned*  pairs   = (unsigned*)carve((size_t)E * 4);
  int*       hist    = (int*)carve((size_t)CB * MAXBUCK * 4);
  int*       totals  = (int*)carve((size_t)(MAXBUCK + 1) * 4);
  int*       bbase   = (int*)carve((size_t)(MAXBUCK + 1) * 4);
  _Float16*  WtAll   = (_Float16*)carve(7 * 16384 * 2);
  float*     gsum    = (float*)carve(16 * H * 4);
  float*     gcnt    = (float*)carve(16 * 4);

  prep_weights<<<(7 * 16384 + 255) / 256, 256, 0, stream>>>(W_embed, Wm, WtAll);

  // CSR build (atomic-free at global scope)
  hist_k<<<CB, 1024, 0, stream>>>(ei, E, chunk, hist, nbuck);
  scanb_k<<<nbuck, CB, 0, stream>>>(hist, totals, nbuck);
  scant_k<<<1, MAXBUCK, 0, stream>>>(totals, bbase, row_ptr, nbuck, E, N, gsum, gcnt);
  scat_k<<<CB, 1024, 0, stream>>>(ei, E, chunk, hist, bbase, pairs, nbuck);
  build_k<<<nbuck, 256, 0, stream>>>(pairs, bbase, row_ptr, srcs, N);

  int ntiles = N / 16;
  gemm_embed<<<512, 256, 0, stream>>>(x, WtAll, b_embed, hh, ntiles);
  for (int l = 0; l < 3; ++l) {
    gemm_pair<<<512, 256, 0, stream>>>(hh, WtAll + (1 + 2 * l) * 16384,
                                       WtAll + (2 + 2 * l) * 16384, bm + l * H,
                                       row_ptr, Pbuf, aggH, ntiles);
    agg_update<<<(N + 3) / 4, 256, 0, stream>>>(Pbuf, row_ptr, srcs, aggH, hh, N);
  }
  pool_k<<<512, 256, 0, stream>>>(hh, batch, gsum, gcnt, N);
  readout_k<<<16, HH2, 0, stream>>>(gsum, gcnt, W1, b1, W2, b2, out);
}

// Round 7
// 408.199 us; speedup vs baseline: 1.1212x; 1.1212x over previous
//
#include <hip/hip_runtime.h>

typedef _Float16 h8 __attribute__((ext_vector_type(8)));
typedef _Float16 h2 __attribute__((ext_vector_type(2)));
typedef float f4 __attribute__((ext_vector_type(4)));
typedef unsigned u4 __attribute__((ext_vector_type(4)));

#define H 128
#define HH2 256
#define M_OUT 2048
#define CB 128           // chunk blocks for histogram/scatter
#define MAXBUCK 1024     // supports N <= 131072

__device__ __forceinline__ float u2f_lo(unsigned v) {
  union { unsigned short s; _Float16 h; } c; c.s = (unsigned short)(v & 0xffffu); return (float)c.h;
}
__device__ __forceinline__ float u2f_hi(unsigned v) {
  union { unsigned short s; _Float16 h; } c; c.s = (unsigned short)(v >> 16); return (float)c.h;
}
__device__ __forceinline__ h2 as_h2(unsigned v) {
  union { unsigned u; h2 h; } c; c.u = v; return c.h;
}

// ---- weight prep: transpose + fp16 convert. mat 0 = W_embed, 1+2l = Wtop_l, 2+2l = Wbot_l
__global__ void prep_weights(const float* __restrict__ We, const float* __restrict__ Wm,
                             _Float16* __restrict__ WtAll) {
  int gid = blockIdx.x * 256 + threadIdx.x;
  if (gid >= 7 * 16384) return;
  int m = gid >> 14, rem = gid & 16383, c = rem >> 7, k = rem & 127;
  float v;
  if (m == 0) v = We[k * H + c];
  else {
    int l = (m - 1) >> 1, bot = (m - 1) & 1;
    v = Wm[l * (2 * H * H) + (bot * H + k) * H + c];
  }
  WtAll[m * 16384 + c * H + k] = (_Float16)v;   // row = out-col, contiguous k
}

// ================= CSR build: atomic-free two-level counting sort =================
// bucket = tgt >> 7  (128 nodes/bucket)

__global__ void hist_k(const int* __restrict__ ei, int E, int chunk,
                       int* __restrict__ hist, int nbuck) {
  __shared__ int bins[MAXBUCK];
  for (int i = threadIdx.x; i < nbuck; i += blockDim.x) bins[i] = 0;
  __syncthreads();
  int s = blockIdx.x * chunk, e = min(s + chunk, E);
  for (int i = s + threadIdx.x; i < e; i += blockDim.x)
    atomicAdd(&bins[ei[E + i] >> 7], 1);
  __syncthreads();
  for (int i = threadIdx.x; i < nbuck; i += blockDim.x)
    hist[blockIdx.x * nbuck + i] = bins[i];
}

// per-bucket exclusive scan over the CB blocks; totals[j] = bucket size
__global__ void scanb_k(int* __restrict__ hist, int* __restrict__ totals, int nbuck) {
  __shared__ int sm[CB];
  int j = blockIdx.x, b = threadIdx.x;
  int v = hist[b * nbuck + j];
  sm[b] = v; __syncthreads();
  for (int off = 1; off < CB; off <<= 1) {
    int add = (b >= off) ? sm[b - off] : 0; __syncthreads();
    sm[b] += add; __syncthreads();
  }
  hist[b * nbuck + j] = sm[b] - v;      // exclusive over blocks
  if (b == CB - 1) totals[j] = sm[b];
}

// exclusive scan of bucket totals -> bucket_base; also zeroes gsum/gcnt for pool
__global__ void scant_k(const int* __restrict__ totals, int* __restrict__ bbase,
                        int* __restrict__ rowp, int nbuck, int E, int N,
                        float* __restrict__ gsum, float* __restrict__ gcnt) {
  __shared__ int sm[MAXBUCK];
  int t = threadIdx.x;
  int v = (t < nbuck) ? totals[t] : 0;
  sm[t] = v; __syncthreads();
  for (int off = 1; off < MAXBUCK; off <<= 1) {
    int add = (t >= off) ? sm[t - off] : 0; __syncthreads();
    sm[t] += add; __syncthreads();
  }
  if (t < nbuck) bbase[t] = sm[t] - v;
  if (t == 0) { bbase[nbuck] = E; rowp[N] = E; }
  for (int i = t; i < 16 * H; i += MAXBUCK) gsum[i] = 0.f;
  if (t < 16) gcnt[t] = 0.f;
}

// scatter packed (ltgt<<25)|src into bucket-major order, LDS cursors (no global atomics)
__global__ void scat_k(const int* __restrict__ ei, int E, int chunk,
                       const int* __restrict__ hist, const int* __restrict__ bbase,
                       unsigned* __restrict__ pairs, int nbuck) {
  __shared__ int cur[MAXBUCK];
  for (int i = threadIdx.x; i < nbuck; i += blockDim.x)
    cur[i] = bbase[i] + hist[blockIdx.x * nbuck + i];
  __syncthreads();
  int s = blockIdx.x * chunk, e = min(s + chunk, E);
  for (int i = s + threadIdx.x; i < e; i += blockDim.x) {
    int sv = ei[i], tv = ei[E + i];
    int pos = atomicAdd(&cur[tv >> 7], 1);
    pairs[pos] = ((unsigned)(tv & 127) << 25) | (unsigned)sv;
  }
}

// per-bucket counting sort: 128-bin LDS histogram + scan -> row_ptr, then scatter srcs
__global__ void build_k(const unsigned* __restrict__ pairs, const int* __restrict__ bbase,
                        int* __restrict__ rowp, int* __restrict__ srcs, int N) {
  __shared__ int h128[128];
  __shared__ int pre[128];
  int j = blockIdx.x, t = threadIdx.x;
  int base = bbase[j], end = bbase[j + 1];
  if (t < 128) h128[t] = 0;
  __syncthreads();
  for (int i = base + t; i < end; i += blockDim.x)
    atomicAdd(&h128[pairs[i] >> 25], 1);
  __syncthreads();
  if (t < 128) pre[t] = h128[t];
  __syncthreads();
  for (int off = 1; off < 128; off <<= 1) {
    int add = (t < 128 && t >= off) ? pre[t - off] : 0; __syncthreads();
    if (t < 128) pre[t] += add; __syncthreads();
  }
  if (t < 128) {
    int excl = pre[t] - h128[t];
    int node = j * 128 + t;
    if (node < N) rowp[node] = base + excl;
    h128[t] = excl;                        // reuse as cursor
  }
  __syncthreads();
  for (int i = base + t; i < end; i += blockDim.x) {
    unsigned p = pairs[i];
    int pos = atomicAdd(&h128[p >> 25], 1);
    srcs[base + pos] = (int)(p & 0x1ffffff);
  }
}

// ================= embed GEMM: hh = fp16(x @ W_embed + b_embed) =================
__global__ __launch_bounds__(256, 2) void gemm_embed(
    const float* __restrict__ Af, const _Float16* __restrict__ Wt,
    const float* __restrict__ bias, _Float16* __restrict__ outH, int ntiles)
{
  int lane = threadIdx.x & 63;
  int wid = blockIdx.x * 4 + (threadIdx.x >> 6);
  int nw = gridDim.x * 4;
  int sel = lane & 15, kg = lane >> 4;

  h8 bfrag[8][4];
#pragma unroll
  for (int ct = 0; ct < 8; ++ct)
#pragma unroll
    for (int ks = 0; ks < 4; ++ks)
      bfrag[ct][ks] = *(const h8*)(Wt + (ct * 16 + sel) * H + ks * 32 + kg * 8);

  auto load_a = [&](int row, int ks) -> h8 {
    const float* b = Af + row * H + ks * 32 + kg * 8;
    f4 a0 = *(const f4*)b, a1 = *(const f4*)(b + 4);
    h8 r;
    r[0] = (_Float16)a0.x; r[1] = (_Float16)a0.y; r[2] = (_Float16)a0.z; r[3] = (_Float16)a0.w;
    r[4] = (_Float16)a1.x; r[5] = (_Float16)a1.y; r[6] = (_Float16)a1.z; r[7] = (_Float16)a1.w;
    return r;
  };

  int t = wid;
  h8 afrag[4];
  if (t < ntiles) {
#pragma unroll
    for (int ks = 0; ks < 4; ++ks) afrag[ks] = load_a(t * 16 + sel, ks);
  }
  while (t < ntiles) {
    int tn = t + nw;
    h8 anext[4];
    if (tn < ntiles) {
#pragma unroll
      for (int ks = 0; ks < 4; ++ks) anext[ks] = load_a(tn * 16 + sel, ks);
    }
    f4 acc[8];
#pragma unroll
    for (int ct = 0; ct < 8; ++ct) acc[ct] = (f4){0.f, 0.f, 0.f, 0.f};
#pragma unroll
    for (int ks = 0; ks < 4; ++ks)
#pragma unroll
      for (int ct = 0; ct < 8; ++ct)
        acc[ct] = __builtin_amdgcn_mfma_f32_16x16x32_f16(afrag[ks], bfrag[ct][ks], acc[ct], 0, 0, 0);
#pragma unroll
    for (int ct = 0; ct < 8; ++ct) {
      int c = ct * 16 + sel;
      float bv = bias[c];
#pragma unroll
      for (int j = 0; j < 4; ++j) {
        int r = t * 16 + kg * 4 + j;
        outH[r * H + c] = (_Float16)(acc[ct][j] + bv);
      }
    }
#pragma unroll
    for (int ks = 0; ks < 4; ++ks) afrag[ks] = anext[ks];
    t = tn;
  }
}

// ================= paired message GEMM (wave-specialized) =================
// waves 0-1: Pout = fp16(hh @ Wtop)
// waves 2-3: aggH = fp16((hh @ Wbot + bm) * indeg)
// Paired waves process the same tile sequence -> hh read once, L1/L2 shared.
__global__ __launch_bounds__(256, 2) void gemm_pair(
    const _Float16* __restrict__ Ah, const _Float16* __restrict__ WtTop,
    const _Float16* __restrict__ WtBot, const float* __restrict__ bias,
    const int* __restrict__ row_ptr, _Float16* __restrict__ Pout,
    _Float16* __restrict__ aggH, int ntiles)
{
  int lane = threadIdx.x & 63;
  int wiw = threadIdx.x >> 6;          // 0..3
  int role = wiw >> 1;                 // 0: P, 1: aggQ
  int wid = blockIdx.x * 2 + (wiw & 1);
  int nw = gridDim.x * 2;
  int sel = lane & 15, kg = lane >> 4;
  const _Float16* Wt = role ? WtBot : WtTop;

  h8 bfrag[8][4];
#pragma unroll
  for (int ct = 0; ct < 8; ++ct)
#pragma unroll
    for (int ks = 0; ks < 4; ++ks)
      bfrag[ct][ks] = *(const h8*)(Wt + (ct * 16 + sel) * H + ks * 32 + kg * 8);

  int t = wid;
  h8 afrag[4];
  if (t < ntiles) {
#pragma unroll
    for (int ks = 0; ks < 4; ++ks)
      afrag[ks] = *(const h8*)(Ah + (t * 16 + sel) * H + ks * 32 + kg * 8);
  }
  while (t < ntiles) {
    int tn = t + nw;
    h8 anext[4];
    if (tn < ntiles) {
#pragma unroll
      for (int ks = 0; ks < 4; ++ks)
        anext[ks] = *(const h8*)(Ah + (tn * 16 + sel) * H + ks * 32 + kg * 8);
    }
    f4 acc[8];
#pragma unroll
    for (int ct = 0; ct < 8; ++ct) acc[ct] = (f4){0.f, 0.f, 0.f, 0.f};
#pragma unroll
    for (int ks = 0; ks < 4; ++ks)
#pragma unroll
      for (int ct = 0; ct < 8; ++ct)
        acc[ct] = __builtin_amdgcn_mfma_f32_16x16x32_f16(afrag[ks], bfrag[ct][ks], acc[ct], 0, 0, 0);

    if (role == 0) {
#pragma unroll
      for (int ct = 0; ct < 8; ++ct) {
        int c = ct * 16 + sel;
#pragma unroll
        for (int j = 0; j < 4; ++j) {
          int r = t * 16 + kg * 4 + j;
          Pout[r * H + c] = (_Float16)acc[ct][j];
        }
      }
    } else {
      float indeg[4];
#pragma unroll
      for (int j = 0; j < 4; ++j) {
        int r = t * 16 + kg * 4 + j;
        indeg[j] = (float)(row_ptr[r + 1] - row_ptr[r]);
      }
#pragma unroll
      for (int ct = 0; ct < 8; ++ct) {
        int c = ct * 16 + sel;
        float bv = bias[c];
#pragma unroll
        for (int j = 0; j < 4; ++j) {
          int r = t * 16 + kg * 4 + j;
          aggH[r * H + c] = (_Float16)((acc[ct][j] + bv) * indeg[j]);
        }
      }
    }
#pragma unroll
    for (int ks = 0; ks < 4; ++ks) afrag[ks] = anext[ks];
    t = tn;
  }
}

// ---- per-node gather of P rows + h update: hh = relu(hh + aggH + sum P[src])
// Quarter-wave (16 lanes x uint4 = 256B) reads one P row -> 4 edges per step.
// Packed fp16 accumulate; fp32 finish. All shfls at wave-uniform control points.
// Streaming operands (srcs, aggH, hh) use nontemporal hints to keep L2 for P.
__global__ __launch_bounds__(256) void agg_update(
    const _Float16* __restrict__ P, const int* __restrict__ rowp,
    const int* __restrict__ srcs, const _Float16* __restrict__ aggH,
    _Float16* hh, int N)
{
  int node = blockIdx.x * 4 + (threadIdx.x >> 6);
  if (node >= N) return;
  int lane = threadIdx.x & 63;
  int q = lane >> 4, li = lane & 15;
  const uint4* P4 = (const uint4*)P;
  h2 a0 = (h2)0, a1 = (h2)0, a2 = (h2)0, a3 = (h2)0;
  int e = rowp[node], end = rowp[node + 1];
  while (e < end) {
    int cnt = min(end - e, 64);          // wave-uniform
    int myS = (lane < cnt) ? __builtin_nontemporal_load(&srcs[e + lane]) : 0;
    int j = 0;
    for (; j + 16 <= cnt; j += 16) {     // 16 edges, 4 loads in flight
      int s0 = __shfl(myS, j + q);
      int s1 = __shfl(myS, j + 4 + q);
      int s2 = __shfl(myS, j + 8 + q);
      int s3 = __shfl(myS, j + 12 + q);
      uint4 v0 = P4[s0 * 16 + li], v1 = P4[s1 * 16 + li];
      uint4 v2 = P4[s2 * 16 + li], v3 = P4[s3 * 16 + li];
      a0 += as_h2(v0.x) + as_h2(v1.x) + as_h2(v2.x) + as_h2(v3.x);
      a1 += as_h2(v0.y) + as_h2(v1.y) + as_h2(v2.y) + as_h2(v3.y);
      a2 += as_h2(v0.z) + as_h2(v1.z) + as_h2(v2.z) + as_h2(v3.z);
      a3 += as_h2(v0.w) + as_h2(v1.w) + as_h2(v2.w) + as_h2(v3.w);
    }
    for (; j + 8 <= cnt; j += 8) {       // 8 edges, 2 loads
      int s0 = __shfl(myS, j + q);
      int s1 = __shfl(myS, j + 4 + q);
      uint4 v0 = P4[s0 * 16 + li], v1 = P4[s1 * 16 + li];
      a0 += as_h2(v0.x) + as_h2(v1.x);
      a1 += as_h2(v0.y) + as_h2(v1.y);
      a2 += as_h2(v0.z) + as_h2(v1.z);
      a3 += as_h2(v0.w) + as_h2(v1.w);
    }
    for (; j < cnt; j += 4) {            // tail: predicated load, uniform shfl exec
      int jj = j + q;
      int s = __shfl(myS, (jj < cnt) ? jj : (cnt - 1));
      if (jj < cnt) {
        uint4 v = P4[s * 16 + li];
        a0 += as_h2(v.x); a1 += as_h2(v.y);
        a2 += as_h2(v.z); a3 += as_h2(v.w);
      }
    }
    e += cnt;
  }
  // unpack to fp32, reduce across the 4 quarter-waves
  float f[8] = { (float)a0[0], (float)a0[1], (float)a1[0], (float)a1[1],
                 (float)a2[0], (float)a2[1], (float)a3[0], (float)a3[1] };
#pragma unroll
  for (int i = 0; i < 8; ++i) {
    f[i] += __shfl_xor(f[i], 16);
    f[i] += __shfl_xor(f[i], 32);
  }
  if (q == 0) {
    int idx = node * 16 + li;            // row = 16 uint4
    u4 hv = __builtin_nontemporal_load(((const u4*)hh) + idx);
    u4 av = __builtin_nontemporal_load(((const u4*)aggH) + idx);
    union { _Float16 h[8]; u4 u; } pk;
#pragma unroll
    for (int i = 0; i < 4; ++i) {
      float r0 = fmaxf(u2f_lo(hv[i]) + u2f_lo(av[i]) + f[2 * i], 0.f);
      float r1 = fmaxf(u2f_hi(hv[i]) + u2f_hi(av[i]) + f[2 * i + 1], 0.f);
      pk.h[2 * i] = (_Float16)r0; pk.h[2 * i + 1] = (_Float16)r1;
    }
    __builtin_nontemporal_store(pk.u, ((u4*)hh) + idx);
  }
}

// ---- mean pool (batch sorted): fp16 input, 4 row-substreams x 64 u32-cols
__global__ void pool_k(const _Float16* __restrict__ hh, const int* __restrict__ batch,
                       float* __restrict__ gsum, float* __restrict__ gcnt, int N)
{
  int t = threadIdx.x, c2 = t & 63, sub = t >> 6;
  int per = (N + gridDim.x - 1) / gridDim.x;
  int s = blockIdx.x * per;
  int e = s + per; if (e > N) e = N;
  const unsigned* hu = (const unsigned*)hh;
  float a0 = 0.f, a1 = 0.f; int cnt = 0, cur = -1;
  for (int n = s + sub; n < e; n += 4) {
    int b = batch[n];
    if (b != cur) {
      if (cur >= 0) {
        atomicAdd(&gsum[cur * H + c2 * 2], a0);
        atomicAdd(&gsum[cur * H + c2 * 2 + 1], a1);
        if (c2 == 0) atomicAdd(&gcnt[cur], (float)cnt);
      }
      a0 = 0.f; a1 = 0.f; cnt = 0; cur = b;
    }
    unsigned v = __builtin_nontemporal_load(&hu[n * 64 + c2]);
    a0 += u2f_lo(v); a1 += u2f_hi(v); ++cnt;
  }
  if (cur >= 0) {
    atomicAdd(&gsum[cur * H + c2 * 2], a0);
    atomicAdd(&gsum[cur * H + c2 * 2 + 1], a1);
    if (c2 == 0) atomicAdd(&gcnt[cur], (float)cnt);
  }
}

__global__ void readout1(const float* __restrict__ gsum, const float* __restrict__ gcnt,
                         const float* __restrict__ W1, const float* __restrict__ b1,
                         float* __restrict__ hidden)
{
  int b = blockIdx.x, j = threadIdx.x;
  __shared__ float g[H];
  if (j < H) g[j] = gsum[b * H + j] / fmaxf(gcnt[b], 1.f);
  __syncthreads();
  float s = b1[j];
  for (int k = 0; k < H; ++k) s += g[k] * W1[k * HH2 + j];
  hidden[b * HH2 + j] = fmaxf(s, 0.f);
}

__global__ void readout2(const float* __restrict__ hidden, const float* __restrict__ W2,
                         const float* __restrict__ b2, float* __restrict__ out)
{
  int gid = blockIdx.x * 256 + threadIdx.x;
  int b = gid >> 11, m = gid & 2047;
  __shared__ float hs[HH2];
  hs[threadIdx.x] = hidden[b * HH2 + threadIdx.x];
  __syncthreads();
  float s = b2[m];
  for (int j = 0; j < HH2; ++j) s += hs[j] * W2[j * M_OUT + m];
  out[gid] = 6.283185307179586f / (1.f + expf(-s));
}

extern "C" void kernel_launch(void* const* d_in, const int* in_sizes, int n_in,
                              void* d_out, int out_size, void* d_ws, size_t ws_size,
                              hipStream_t stream) {
  const float* x       = (const float*)d_in[0];
  const int*   ei      = (const int*)d_in[1];
  const int*   batch   = (const int*)d_in[2];
  const float* W_embed = (const float*)d_in[3];
  const float* b_embed = (const float*)d_in[4];
  const float* Wm      = (const float*)d_in[5];
  const float* bm      = (const float*)d_in[6];
  const float* W1      = (const float*)d_in[7];
  const float* b1      = (const float*)d_in[8];
  const float* W2      = (const float*)d_in[9];
  const float* b2      = (const float*)d_in[10];
  float* out = (float*)d_out;

  const int N = in_sizes[0] / H;
  const int E = in_sizes[1] / 2;
  const int nbuck = (N + 127) >> 7;
  const int chunk = (E + CB - 1) / CB;

  char* p = (char*)d_ws;
  auto carve = [&](size_t bytes) { void* r = (void*)p; p += (bytes + 255) & ~(size_t)255; return r; };
  _Float16*  hh      = (_Float16*)carve((size_t)N * H * 2);
  _Float16*  aggH    = (_Float16*)carve((size_t)N * H * 2);
  _Float16*  Pbuf    = (_Float16*)carve((size_t)N * H * 2);
  int*       row_ptr = (int*)carve((size_t)(N + 1) * 4);
  int*       srcs    = (int*)carve((size_t)E * 4);
  unsigned*  pairs   = (unsigned*)carve((size_t)E * 4);
  int*       hist    = (int*)carve((size_t)CB * MAXBUCK * 4);
  int*       totals  = (int*)carve((size_t)(MAXBUCK + 1) * 4);
  int*       bbase   = (int*)carve((size_t)(MAXBUCK + 1) * 4);
  _Float16*  WtAll   = (_Float16*)carve(7 * 16384 * 2);
  float*     gsum    = (float*)carve(16 * H * 4);
  float*     gcnt    = (float*)carve(16 * 4);
  float*     hidden  = (float*)carve(16 * HH2 * 4);

  prep_weights<<<(7 * 16384 + 255) / 256, 256, 0, stream>>>(W_embed, Wm, WtAll);

  // CSR build (atomic-free at global scope)
  hist_k<<<CB, 1024, 0, stream>>>(ei, E, chunk, hist, nbuck);
  scanb_k<<<nbuck, CB, 0, stream>>>(hist, totals, nbuck);
  scant_k<<<1, MAXBUCK, 0, stream>>>(totals, bbase, row_ptr, nbuck, E, N, gsum, gcnt);
  scat_k<<<CB, 1024, 0, stream>>>(ei, E, chunk, hist, bbase, pairs, nbuck);
  build_k<<<nbuck, 256, 0, stream>>>(pairs, bbase, row_ptr, srcs, N);

  int ntiles = N / 16;
  gemm_embed<<<512, 256, 0, stream>>>(x, WtAll, b_embed, hh, ntiles);
  for (int l = 0; l < 3; ++l) {
    gemm_pair<<<512, 256, 0, stream>>>(hh, WtAll + (1 + 2 * l) * 16384,
                                       WtAll + (2 + 2 * l) * 16384, bm + l * H,
                                       row_ptr, Pbuf, aggH, ntiles);
    agg_update<<<(N + 3) / 4, 256, 0, stream>>>(Pbuf, row_ptr, srcs, aggH, hh, N);
  }
  pool_k<<<512, 256, 0, stream>>>(hh, batch, gsum, gcnt, N);
  readout1<<<16, HH2, 0, stream>>>(gsum, gcnt, W1, b1, hidden);
  readout2<<<16 * M_OUT / 256, 256, 0, stream>>>(hidden, W2, b2, out);
}

// Round 8
// 395.593 us; speedup vs baseline: 1.1569x; 1.0319x over previous
//
#include <hip/hip_runtime.h>

typedef _Float16 h8 __attribute__((ext_vector_type(8)));
typedef _Float16 h2 __attribute__((ext_vector_type(2)));
typedef float f4 __attribute__((ext_vector_type(4)));
typedef unsigned u4 __attribute__((ext_vector_type(4)));

#define H 128
#define HH2 256
#define M_OUT 2048
#define CB 128           // chunk blocks for histogram/scatter
#define MAXBUCK 1024     // supports N <= 131072

__device__ __forceinline__ float u2f_lo(unsigned v) {
  union { unsigned short s; _Float16 h; } c; c.s = (unsigned short)(v & 0xffffu); return (float)c.h;
}
__device__ __forceinline__ float u2f_hi(unsigned v) {
  union { unsigned short s; _Float16 h; } c; c.s = (unsigned short)(v >> 16); return (float)c.h;
}
__device__ __forceinline__ h2 as_h2(unsigned v) {
  union { unsigned u; h2 h; } c; c.u = v; return c.h;
}

// ================= merged: CSR histogram (blocks 0..CB-1) + weight prep =================
// prep: mat 0 = W_embed, 1+2l = Wtop_l, 2+2l = Wbot_l ; row = out-col, contiguous k
__global__ void csr0_k(const int* __restrict__ ei, int E, int chunk,
                       int* __restrict__ hist, int nbuck,
                       const float* __restrict__ We, const float* __restrict__ Wm,
                       _Float16* __restrict__ WtAll) {
  if (blockIdx.x < CB) {
    __shared__ int bins[MAXBUCK];
    for (int i = threadIdx.x; i < nbuck; i += blockDim.x) bins[i] = 0;
    __syncthreads();
    int s = blockIdx.x * chunk, e = min(s + chunk, E);
    for (int i = s + threadIdx.x; i < e; i += blockDim.x)
      atomicAdd(&bins[ei[E + i] >> 7], 1);
    __syncthreads();
    for (int i = threadIdx.x; i < nbuck; i += blockDim.x)
      hist[blockIdx.x * nbuck + i] = bins[i];
  } else {
    int gid = (blockIdx.x - CB) * 1024 + threadIdx.x;
    if (gid >= 7 * 16384) return;
    int m = gid >> 14, rem = gid & 16383, c = rem >> 7, k = rem & 127;
    float v;
    if (m == 0) v = We[k * H + c];
    else {
      int l = (m - 1) >> 1, bot = (m - 1) & 1;
      v = Wm[l * (2 * H * H) + (bot * H + k) * H + c];
    }
    WtAll[m * 16384 + c * H + k] = (_Float16)v;
  }
}

// per-bucket exclusive scan over the CB blocks; totals[j] = bucket size
__global__ void scanb_k(int* __restrict__ hist, int* __restrict__ totals, int nbuck) {
  __shared__ int sm[CB];
  int j = blockIdx.x, b = threadIdx.x;
  int v = hist[b * nbuck + j];
  sm[b] = v; __syncthreads();
  for (int off = 1; off < CB; off <<= 1) {
    int add = (b >= off) ? sm[b - off] : 0; __syncthreads();
    sm[b] += add; __syncthreads();
  }
  hist[b * nbuck + j] = sm[b] - v;      // exclusive over blocks
  if (b == CB - 1) totals[j] = sm[b];
}

// exclusive scan of bucket totals -> bucket_base; also zeroes gsum/gcnt for pool
__global__ void scant_k(const int* __restrict__ totals, int* __restrict__ bbase,
                        int* __restrict__ rowp, int nbuck, int E, int N,
                        float* __restrict__ gsum, float* __restrict__ gcnt) {
  __shared__ int sm[MAXBUCK];
  int t = threadIdx.x;
  int v = (t < nbuck) ? totals[t] : 0;
  sm[t] = v; __syncthreads();
  for (int off = 1; off < MAXBUCK; off <<= 1) {
    int add = (t >= off) ? sm[t - off] : 0; __syncthreads();
    sm[t] += add; __syncthreads();
  }
  if (t < nbuck) bbase[t] = sm[t] - v;
  if (t == 0) { bbase[nbuck] = E; rowp[N] = E; }
  for (int i = t; i < 16 * H; i += MAXBUCK) gsum[i] = 0.f;
  if (t < 16) gcnt[t] = 0.f;
}

// scatter packed (ltgt<<25)|src into bucket-major order, LDS cursors (no global atomics)
__global__ void scat_k(const int* __restrict__ ei, int E, int chunk,
                       const int* __restrict__ hist, const int* __restrict__ bbase,
                       unsigned* __restrict__ pairs, int nbuck) {
  __shared__ int cur[MAXBUCK];
  for (int i = threadIdx.x; i < nbuck; i += blockDim.x)
    cur[i] = bbase[i] + hist[blockIdx.x * nbuck + i];
  __syncthreads();
  int s = blockIdx.x * chunk, e = min(s + chunk, E);
  for (int i = s + threadIdx.x; i < e; i += blockDim.x) {
    int sv = ei[i], tv = ei[E + i];
    int pos = atomicAdd(&cur[tv >> 7], 1);
    pairs[pos] = ((unsigned)(tv & 127) << 25) | (unsigned)sv;
  }
}

// per-bucket counting sort: 128-bin LDS histogram + scan -> row_ptr, then scatter srcs
__global__ void build_k(const unsigned* __restrict__ pairs, const int* __restrict__ bbase,
                        int* __restrict__ rowp, int* __restrict__ srcs, int N) {
  __shared__ int h128[128];
  __shared__ int pre[128];
  int j = blockIdx.x, t = threadIdx.x;
  int base = bbase[j], end = bbase[j + 1];
  if (t < 128) h128[t] = 0;
  __syncthreads();
  for (int i = base + t; i < end; i += blockDim.x)
    atomicAdd(&h128[pairs[i] >> 25], 1);
  __syncthreads();
  if (t < 128) pre[t] = h128[t];
  __syncthreads();
  for (int off = 1; off < 128; off <<= 1) {
    int add = (t < 128 && t >= off) ? pre[t - off] : 0; __syncthreads();
    if (t < 128) pre[t] += add; __syncthreads();
  }
  if (t < 128) {
    int excl = pre[t] - h128[t];
    int node = j * 128 + t;
    if (node < N) rowp[node] = base + excl;
    h128[t] = excl;                        // reuse as cursor
  }
  __syncthreads();
  for (int i = base + t; i < end; i += blockDim.x) {
    unsigned p = pairs[i];
    int pos = atomicAdd(&h128[p >> 25], 1);
    srcs[base + pos] = (int)(p & 0x1ffffff);
  }
}

// ================= embed GEMM: hh = fp16(x @ W_embed + b_embed) =================
__global__ __launch_bounds__(256, 2) void gemm_embed(
    const float* __restrict__ Af, const _Float16* __restrict__ Wt,
    const float* __restrict__ bias, _Float16* __restrict__ outH, int ntiles)
{
  int lane = threadIdx.x & 63;
  int wid = blockIdx.x * 4 + (threadIdx.x >> 6);
  int nw = gridDim.x * 4;
  int sel = lane & 15, kg = lane >> 4;

  h8 bfrag[8][4];
#pragma unroll
  for (int ct = 0; ct < 8; ++ct)
#pragma unroll
    for (int ks = 0; ks < 4; ++ks)
      bfrag[ct][ks] = *(const h8*)(Wt + (ct * 16 + sel) * H + ks * 32 + kg * 8);

  auto load_a = [&](int row, int ks) -> h8 {
    const float* b = Af + row * H + ks * 32 + kg * 8;
    f4 a0 = *(const f4*)b, a1 = *(const f4*)(b + 4);
    h8 r;
    r[0] = (_Float16)a0.x; r[1] = (_Float16)a0.y; r[2] = (_Float16)a0.z; r[3] = (_Float16)a0.w;
    r[4] = (_Float16)a1.x; r[5] = (_Float16)a1.y; r[6] = (_Float16)a1.z; r[7] = (_Float16)a1.w;
    return r;
  };

  int t = wid;
  h8 afrag[4];
  if (t < ntiles) {
#pragma unroll
    for (int ks = 0; ks < 4; ++ks) afrag[ks] = load_a(t * 16 + sel, ks);
  }
  while (t < ntiles) {
    int tn = t + nw;
    h8 anext[4];
    if (tn < ntiles) {
#pragma unroll
      for (int ks = 0; ks < 4; ++ks) anext[ks] = load_a(tn * 16 + sel, ks);
    }
    f4 acc[8];
#pragma unroll
    for (int ct = 0; ct < 8; ++ct) acc[ct] = (f4){0.f, 0.f, 0.f, 0.f};
#pragma unroll
    for (int ks = 0; ks < 4; ++ks)
#pragma unroll
      for (int ct = 0; ct < 8; ++ct)
        acc[ct] = __builtin_amdgcn_mfma_f32_16x16x32_f16(afrag[ks], bfrag[ct][ks], acc[ct], 0, 0, 0);
#pragma unroll
    for (int ct = 0; ct < 8; ++ct) {
      int c = ct * 16 + sel;
      float bv = bias[c];
#pragma unroll
      for (int j = 0; j < 4; ++j) {
        int r = t * 16 + kg * 4 + j;
        outH[r * H + c] = (_Float16)(acc[ct][j] + bv);
      }
    }
#pragma unroll
    for (int ks = 0; ks < 4; ++ks) afrag[ks] = anext[ks];
    t = tn;
  }
}

// ================= paired message GEMM (wave-specialized) =================
// waves 0-1: Pout = fp16(hh @ Wtop) ; waves 2-3: aggH = fp16((hh @ Wbot + bm) * indeg)
__global__ __launch_bounds__(256, 2) void gemm_pair(
    const _Float16* __restrict__ Ah, const _Float16* __restrict__ WtTop,
    const _Float16* __restrict__ WtBot, const float* __restrict__ bias,
    const int* __restrict__ row_ptr, _Float16* __restrict__ Pout,
    _Float16* __restrict__ aggH, int ntiles)
{
  int lane = threadIdx.x & 63;
  int wiw = threadIdx.x >> 6;          // 0..3
  int role = wiw >> 1;                 // 0: P, 1: aggQ
  int wid = blockIdx.x * 2 + (wiw & 1);
  int nw = gridDim.x * 2;
  int sel = lane & 15, kg = lane >> 4;
  const _Float16* Wt = role ? WtBot : WtTop;

  h8 bfrag[8][4];
#pragma unroll
  for (int ct = 0; ct < 8; ++ct)
#pragma unroll
    for (int ks = 0; ks < 4; ++ks)
      bfrag[ct][ks] = *(const h8*)(Wt + (ct * 16 + sel) * H + ks * 32 + kg * 8);

  int t = wid;
  h8 afrag[4];
  if (t < ntiles) {
#pragma unroll
    for (int ks = 0; ks < 4; ++ks)
      afrag[ks] = *(const h8*)(Ah + (t * 16 + sel) * H + ks * 32 + kg * 8);
  }
  while (t < ntiles) {
    int tn = t + nw;
    h8 anext[4];
    if (tn < ntiles) {
#pragma unroll
      for (int ks = 0; ks < 4; ++ks)
        anext[ks] = *(const h8*)(Ah + (tn * 16 + sel) * H + ks * 32 + kg * 8);
    }
    f4 acc[8];
#pragma unroll
    for (int ct = 0; ct < 8; ++ct) acc[ct] = (f4){0.f, 0.f, 0.f, 0.f};
#pragma unroll
    for (int ks = 0; ks < 4; ++ks)
#pragma unroll
      for (int ct = 0; ct < 8; ++ct)
        acc[ct] = __builtin_amdgcn_mfma_f32_16x16x32_f16(afrag[ks], bfrag[ct][ks], acc[ct], 0, 0, 0);

    if (role == 0) {
#pragma unroll
      for (int ct = 0; ct < 8; ++ct) {
        int c = ct * 16 + sel;
#pragma unroll
        for (int j = 0; j < 4; ++j) {
          int r = t * 16 + kg * 4 + j;
          Pout[r * H + c] = (_Float16)acc[ct][j];
        }
      }
    } else {
      float indeg[4];
#pragma unroll
      for (int j = 0; j < 4; ++j) {
        int r = t * 16 + kg * 4 + j;
        indeg[j] = (float)(row_ptr[r + 1] - row_ptr[r]);
      }
#pragma unroll
      for (int ct = 0; ct < 8; ++ct) {
        int c = ct * 16 + sel;
        float bv = bias[c];
#pragma unroll
        for (int j = 0; j < 4; ++j) {
          int r = t * 16 + kg * 4 + j;
          aggH[r * H + c] = (_Float16)((acc[ct][j] + bv) * indeg[j]);
        }
      }
    }
#pragma unroll
    for (int ks = 0; ks < 4; ++ks) afrag[ks] = anext[ks];
    t = tn;
  }
}

// ---- per-node gather + update: hh = relu(hh + aggH + sum P[src])
// TWO nodes per wave (A,B contiguous: eB == endA). Quarter-wave (16 lanes x uint4
// = 256B) reads one P row. Interleaved A/B 16-edge batches -> 8 loads in flight;
// tail = one 4-slot pass (clamped shfl idx, unconditional loads, masked adds).
// ALL shfls at wave-uniform control points (cntA/cntB are wave-uniform).
__global__ __launch_bounds__(256) void agg_update(
    const _Float16* __restrict__ P, const int* __restrict__ rowp,
    const int* __restrict__ srcs, const _Float16* __restrict__ aggH,
    _Float16* hh, int N)
{
  int w = blockIdx.x * 4 + (threadIdx.x >> 6);
  int n0 = w * 2;
  if (n0 >= N) return;
  int n1 = n0 + 1;
  bool hasB = (n1 < N);
  int lane = threadIdx.x & 63;
  int q = lane >> 4, li = lane & 15;
  const uint4* P4 = (const uint4*)P;

  int eA = rowp[n0];
  int endA = rowp[n0 + 1];
  int endB = hasB ? rowp[n0 + 2] : endA;
  int eB = endA;

  // hoisted residual loads on the write lanes (q0 -> A, q1 -> B)
  int idx = (q == 0 ? n0 : n1) * 16 + li;
  u4 hv = (u4)0, av = (u4)0;
  bool doW = (q == 0) || (q == 1 && hasB);
  if (doW) {
    hv = __builtin_nontemporal_load(((const u4*)hh) + idx);
    av = __builtin_nontemporal_load(((const u4*)aggH) + idx);
  }

  h2 aA0 = (h2)0, aA1 = (h2)0, aA2 = (h2)0, aA3 = (h2)0;
  h2 aB0 = (h2)0, aB1 = (h2)0, aB2 = (h2)0, aB3 = (h2)0;

  while (eA < endA || eB < endB) {
    int cntA = min(max(endA - eA, 0), 64);   // wave-uniform
    int cntB = min(max(endB - eB, 0), 64);   // wave-uniform
    int mySA = (lane < cntA) ? __builtin_nontemporal_load(&srcs[eA + lane]) : 0;
    int mySB = (lane < cntB) ? __builtin_nontemporal_load(&srcs[eB + lane]) : 0;
    int jA = 0, jB = 0;
    // interleaved full batches: 8 loads in flight
    while (jA + 16 <= cntA && jB + 16 <= cntB) {
      int sA0 = __shfl(mySA, jA + q),     sA1 = __shfl(mySA, jA + 4 + q);
      int sA2 = __shfl(mySA, jA + 8 + q), sA3 = __shfl(mySA, jA + 12 + q);
      int sB0 = __shfl(mySB, jB + q),     sB1 = __shfl(mySB, jB + 4 + q);
      int sB2 = __shfl(mySB, jB + 8 + q), sB3 = __shfl(mySB, jB + 12 + q);
      uint4 vA0 = P4[sA0 * 16 + li], vA1 = P4[sA1 * 16 + li];
      uint4 vA2 = P4[sA2 * 16 + li], vA3 = P4[sA3 * 16 + li];
      uint4 vB0 = P4[sB0 * 16 + li], vB1 = P4[sB1 * 16 + li];
      uint4 vB2 = P4[sB2 * 16 + li], vB3 = P4[sB3 * 16 + li];
      aA0 += as_h2(vA0.x) + as_h2(vA1.x) + as_h2(vA2.x) + as_h2(vA3.x);
      aA1 += as_h2(vA0.y) + as_h2(vA1.y) + as_h2(vA2.y) + as_h2(vA3.y);
      aA2 += as_h2(vA0.z) + as_h2(vA1.z) + as_h2(vA2.z) + as_h2(vA3.z);
      aA3 += as_h2(vA0.w) + as_h2(vA1.w) + as_h2(vA2.w) + as_h2(vA3.w);
      aB0 += as_h2(vB0.x) + as_h2(vB1.x) + as_h2(vB2.x) + as_h2(vB3.x);
      aB1 += as_h2(vB0.y) + as_h2(vB1.y) + as_h2(vB2.y) + as_h2(vB3.y);
      aB2 += as_h2(vB0.z) + as_h2(vB1.z) + as_h2(vB2.z) + as_h2(vB3.z);
      aB3 += as_h2(vB0.w) + as_h2(vB1.w) + as_h2(vB2.w) + as_h2(vB3.w);
      jA += 16; jB += 16;
    }
    // drain remaining full batches: A then B (4 loads in flight each)
    while (jA + 16 <= cntA) {
      int s0 = __shfl(mySA, jA + q),     s1 = __shfl(mySA, jA + 4 + q);
      int s2 = __shfl(mySA, jA + 8 + q), s3 = __shfl(mySA, jA + 12 + q);
      uint4 v0 = P4[s0 * 16 + li], v1 = P4[s1 * 16 + li];
      uint4 v2 = P4[s2 * 16 + li], v3 = P4[s3 * 16 + li];
      aA0 += as_h2(v0.x) + as_h2(v1.x) + as_h2(v2.x) + as_h2(v3.x);
      aA1 += as_h2(v0.y) + as_h2(v1.y) + as_h2(v2.y) + as_h2(v3.y);
      aA2 += as_h2(v0.z) + as_h2(v1.z) + as_h2(v2.z) + as_h2(v3.z);
      aA3 += as_h2(v0.w) + as_h2(v1.w) + as_h2(v2.w) + as_h2(v3.w);
      jA += 16;
    }
    while (jB + 16 <= cntB) {
      int s0 = __shfl(mySB, jB + q),     s1 = __shfl(mySB, jB + 4 + q);
      int s2 = __shfl(mySB, jB + 8 + q), s3 = __shfl(mySB, jB + 12 + q);
      uint4 v0 = P4[s0 * 16 + li], v1 = P4[s1 * 16 + li];
      uint4 v2 = P4[s2 * 16 + li], v3 = P4[s3 * 16 + li];
      aB0 += as_h2(v0.x) + as_h2(v1.x) + as_h2(v2.x) + as_h2(v3.x);
      aB1 += as_h2(v0.y) + as_h2(v1.y) + as_h2(v2.y) + as_h2(v3.y);
      aB2 += as_h2(v0.z) + as_h2(v1.z) + as_h2(v2.z) + as_h2(v3.z);
      aB3 += as_h2(v0.w) + as_h2(v1.w) + as_h2(v2.w) + as_h2(v3.w);
      jB += 16;
    }
    // tails (<16 edges): clamped shfl, unconditional loads, masked adds
    if (cntA - jA > 0) {
      int c1 = cntA - 1;
      int j0 = jA + q, j1 = jA + q + 4, j2 = jA + q + 8, j3 = jA + q + 12;
      int s0 = __shfl(mySA, min(j0, c1)), s1 = __shfl(mySA, min(j1, c1));
      int s2 = __shfl(mySA, min(j2, c1)), s3 = __shfl(mySA, min(j3, c1));
      uint4 v0 = P4[s0 * 16 + li], v1 = P4[s1 * 16 + li];
      uint4 v2 = P4[s2 * 16 + li], v3 = P4[s3 * 16 + li];
      if (j0 < cntA) { aA0 += as_h2(v0.x); aA1 += as_h2(v0.y); aA2 += as_h2(v0.z); aA3 += as_h2(v0.w); }
      if (j1 < cntA) { aA0 += as_h2(v1.x); aA1 += as_h2(v1.y); aA2 += as_h2(v1.z); aA3 += as_h2(v1.w); }
      if (j2 < cntA) { aA0 += as_h2(v2.x); aA1 += as_h2(v2.y); aA2 += as_h2(v2.z); aA3 += as_h2(v2.w); }
      if (j3 < cntA) { aA0 += as_h2(v3.x); aA1 += as_h2(v3.y); aA2 += as_h2(v3.z); aA3 += as_h2(v3.w); }
    }
    if (cntB - jB > 0) {
      int c1 = cntB - 1;
      int j0 = jB + q, j1 = jB + q + 4, j2 = jB + q + 8, j3 = jB + q + 12;
      int s0 = __shfl(mySB, min(j0, c1)), s1 = __shfl(mySB, min(j1, c1));
      int s2 = __shfl(mySB, min(j2, c1)), s3 = __shfl(mySB, min(j3, c1));
      uint4 v0 = P4[s0 * 16 + li], v1 = P4[s1 * 16 + li];
      uint4 v2 = P4[s2 * 16 + li], v3 = P4[s3 * 16 + li];
      if (j0 < cntB) { aB0 += as_h2(v0.x); aB1 += as_h2(v0.y); aB2 += as_h2(v0.z); aB3 += as_h2(v0.w); }
      if (j1 < cntB) { aB0 += as_h2(v1.x); aB1 += as_h2(v1.y); aB2 += as_h2(v1.z); aB3 += as_h2(v1.w); }
      if (j2 < cntB) { aB0 += as_h2(v2.x); aB1 += as_h2(v2.y); aB2 += as_h2(v2.z); aB3 += as_h2(v2.w); }
      if (j3 < cntB) { aB0 += as_h2(v3.x); aB1 += as_h2(v3.y); aB2 += as_h2(v3.z); aB3 += as_h2(v3.w); }
    }
    eA += cntA; eB += cntB;
  }

  // unpack to fp32, reduce across the 4 quarter-waves (all lanes get totals)
  float fA[8] = { (float)aA0[0], (float)aA0[1], (float)aA1[0], (float)aA1[1],
                  (float)aA2[0], (float)aA2[1], (float)aA3[0], (float)aA3[1] };
  float fB[8] = { (float)aB0[0], (float)aB0[1], (float)aB1[0], (float)aB1[1],
                  (float)aB2[0], (float)aB2[1], (float)aB3[0], (float)aB3[1] };
#pragma unroll
  for (int i = 0; i < 8; ++i) {
    fA[i] += __shfl_xor(fA[i], 16); fA[i] += __shfl_xor(fA[i], 32);
    fB[i] += __shfl_xor(fB[i], 16); fB[i] += __shfl_xor(fB[i], 32);
  }
  if (doW) {
    union { _Float16 hx[8]; u4 u; } pk;
#pragma unroll
    for (int i = 0; i < 4; ++i) {
      float g0 = (q == 0) ? fA[2 * i]     : fB[2 * i];
      float g1 = (q == 0) ? fA[2 * i + 1] : fB[2 * i + 1];
      float r0 = fmaxf(u2f_lo(hv[i]) + u2f_lo(av[i]) + g0, 0.f);
      float r1 = fmaxf(u2f_hi(hv[i]) + u2f_hi(av[i]) + g1, 0.f);
      pk.hx[2 * i] = (_Float16)r0; pk.hx[2 * i + 1] = (_Float16)r1;
    }
    __builtin_nontemporal_store(pk.u, ((u4*)hh) + idx);
  }
}

// ---- mean pool (batch sorted): fp16 input, 4 row-substreams x 64 u32-cols
__global__ void pool_k(const _Float16* __restrict__ hh, const int* __restrict__ batch,
                       float* __restrict__ gsum, float* __restrict__ gcnt, int N)
{
  int t = threadIdx.x, c2 = t & 63, sub = t >> 6;
  int per = (N + gridDim.x - 1) / gridDim.x;
  int s = blockIdx.x * per;
  int e = s + per; if (e > N) e = N;
  const unsigned* hu = (const unsigned*)hh;
  float a0 = 0.f, a1 = 0.f; int cnt = 0, cur = -1;
  for (int n = s + sub; n < e; n += 4) {
    int b = batch[n];
    if (b != cur) {
      if (cur >= 0) {
        atomicAdd(&gsum[cur * H + c2 * 2], a0);
        atomicAdd(&gsum[cur * H + c2 * 2 + 1], a1);
        if (c2 == 0) atomicAdd(&gcnt[cur], (float)cnt);
      }
      a0 = 0.f; a1 = 0.f; cnt = 0; cur = b;
    }
    unsigned v = __builtin_nontemporal_load(&hu[n * 64 + c2]);
    a0 += u2f_lo(v); a1 += u2f_hi(v); ++cnt;
  }
  if (cur >= 0) {
    atomicAdd(&gsum[cur * H + c2 * 2], a0);
    atomicAdd(&gsum[cur * H + c2 * 2 + 1], a1);
    if (c2 == 0) atomicAdd(&gcnt[cur], (float)cnt);
  }
}

// ---- merged readout, parallel: grid = 16 graphs x 8 m-chunks, hidden recomputed per chunk
__global__ void readout_m(const float* __restrict__ gsum, const float* __restrict__ gcnt,
                          const float* __restrict__ W1, const float* __restrict__ b1,
                          const float* __restrict__ W2, const float* __restrict__ b2,
                          float* __restrict__ out)
{
  int b = blockIdx.x >> 3, chunk = blockIdx.x & 7, j = threadIdx.x;
  __shared__ float g[H];
  __shared__ float hid[HH2];
  if (j < H) g[j] = gsum[b * H + j] / fmaxf(gcnt[b], 1.f);
  __syncthreads();
  float s = b1[j];
  for (int k = 0; k < H; ++k) s += g[k] * W1[k * HH2 + j];
  hid[j] = fmaxf(s, 0.f);
  __syncthreads();
  int m = chunk * 256 + j;
  float v = b2[m];
  for (int k = 0; k < HH2; ++k) v += hid[k] * W2[k * M_OUT + m];
  out[b * M_OUT + m] = 6.283185307179586f / (1.f + expf(-v));
}

extern "C" void kernel_launch(void* const* d_in, const int* in_sizes, int n_in,
                              void* d_out, int out_size, void* d_ws, size_t ws_size,
                              hipStream_t stream) {
  const float* x       = (const float*)d_in[0];
  const int*   ei      = (const int*)d_in[1];
  const int*   batch   = (const int*)d_in[2];
  const float* W_embed = (const float*)d_in[3];
  const float* b_embed = (const float*)d_in[4];
  const float* Wm      = (const float*)d_in[5];
  const float* bm      = (const float*)d_in[6];
  const float* W1      = (const float*)d_in[7];
  const float* b1      = (const float*)d_in[8];
  const float* W2      = (const float*)d_in[9];
  const float* b2      = (const float*)d_in[10];
  float* out = (float*)d_out;

  const int N = in_sizes[0] / H;
  const int E = in_sizes[1] / 2;
  const int nbuck = (N + 127) >> 7;
  const int chunk = (E + CB - 1) / CB;

  char* p = (char*)d_ws;
  auto carve = [&](size_t bytes) { void* r = (void*)p; p += (bytes + 255) & ~(size_t)255; return r; };
  _Float16*  hh      = (_Float16*)carve((size_t)N * H * 2);
  _Float16*  aggH    = (_Float16*)carve((size_t)N * H * 2);
  _Float16*  Pbuf    = (_Float16*)carve((size_t)N * H * 2);
  int*       row_ptr = (int*)carve((size_t)(N + 1) * 4);
  int*       srcs    = (int*)carve((size_t)E * 4);
  unsigned*  pairs   = (unsigned*)carve((size_t)E * 4);
  int*       hist    = (int*)carve((size_t)CB * MAXBUCK * 4);
  int*       totals  = (int*)carve((size_t)(MAXBUCK + 1) * 4);
  int*       bbase   = (int*)carve((size_t)(MAXBUCK + 1) * 4);
  _Float16*  WtAll   = (_Float16*)carve(7 * 16384 * 2);
  float*     gsum    = (float*)carve(16 * H * 4);
  float*     gcnt    = (float*)carve(16 * 4);

  // CSR build + weight prep (merged first kernel)
  csr0_k<<<CB + 112, 1024, 0, stream>>>(ei, E, chunk, hist, nbuck, W_embed, Wm, WtAll);
  scanb_k<<<nbuck, CB, 0, stream>>>(hist, totals, nbuck);
  scant_k<<<1, MAXBUCK, 0, stream>>>(totals, bbase, row_ptr, nbuck, E, N, gsum, gcnt);
  scat_k<<<CB, 1024, 0, stream>>>(ei, E, chunk, hist, bbase, pairs, nbuck);
  build_k<<<nbuck, 256, 0, stream>>>(pairs, bbase, row_ptr, srcs, N);

  int ntiles = N / 16;
  gemm_embed<<<512, 256, 0, stream>>>(x, WtAll, b_embed, hh, ntiles);
  for (int l = 0; l < 3; ++l) {
    gemm_pair<<<512, 256, 0, stream>>>(hh, WtAll + (1 + 2 * l) * 16384,
                                       WtAll + (2 + 2 * l) * 16384, bm + l * H,
                                       row_ptr, Pbuf, aggH, ntiles);
    agg_update<<<(N + 7) / 8, 256, 0, stream>>>(Pbuf, row_ptr, srcs, aggH, hh, N);
  }
  pool_k<<<512, 256, 0, stream>>>(hh, batch, gsum, gcnt, N);
  readout_m<<<16 * 8, HH2, 0, stream>>>(gsum, gcnt, W1, b1, W2, b2, out);
}